// Round 1
// baseline (2971.369 us; speedup 1.0000x reference)
//
#include <hip/hip_runtime.h>
#include <hip/hip_bf16.h>
#include <stdint.h>

#define TT 512
#define BB 256
#define DD 512
#define HH 256
#define AA 32
#define NG 1024  // 4*H

using f32x4 = __attribute__((ext_vector_type(4))) float;
using bf8   = __attribute__((ext_vector_type(8))) short;

static __device__ __forceinline__ short f2bf(float f) {
  union { float f; uint32_t u; } v; v.f = f;
  uint32_t u = v.u;
  u = u + 0x7fffu + ((u >> 16) & 1u);   // round-to-nearest-even
  return (short)(u >> 16);
}
static __device__ __forceinline__ float bf2f(unsigned short s) {
  union { uint32_t u; float f; } v; v.u = ((uint32_t)s) << 16;
  return v.f;
}
static __device__ __forceinline__ float sigf(float x) {
  return 1.0f / (1.0f + __expf(-x));
}
static __device__ __forceinline__ float tanh_(float x) {
  float e = __expf(2.0f * x);
  return 1.0f - 2.0f / (e + 1.0f);   // safe at +/-inf
}

// ---- workspace layout ----
static constexpr size_t XP_OFF    = 0;                              // bf16 [T*B][1024]
static constexpr size_t XP_BYTES  = (size_t)TT * BB * NG * 2;       // 268435456
static constexpr size_t WXT_OFF   = XP_OFF + XP_BYTES;              // bf16 [1024][512]
static constexpr size_t WXT_BYTES = (size_t)NG * DD * 2;            // 1048576
// tagged mail: u32 {low16 = bf16 h, high16 = tag = t+1}
// [parity 2][grp 16][half 2][row 16][hcol 128]
static constexpr size_t MAIL_OFF  = WXT_OFF + WXT_BYTES;
static constexpr size_t MAIL_BYTES= (size_t)2 * 16 * 2 * 16 * 128 * 4;  // 524288
// per-timestep xp readiness tags: u32 done[T][16], value 0x5EED0000|t.
// Poison 0xAAAAAAAA never matches; no init needed (harness poisons ws).
static constexpr size_t DONE_OFF   = MAIL_OFF + MAIL_BYTES;
static constexpr size_t DONE_BYTES = (size_t)TT * 16 * 4;           // 32768
static constexpr size_t WS_NEEDED      = MAIL_OFF + MAIL_BYTES;     // legacy path
static constexpr size_t WS_NEEDED_FUSE = DONE_OFF + DONE_BYTES;     // fused path

// Wx [512][1024] fp32 -> WxT [1024][512] bf16
__global__ __launch_bounds__(256) void transpose_wx_kernel(
    const float* __restrict__ Wx, unsigned short* __restrict__ WxT) {
  __shared__ float tile[32][33];
  int bx = blockIdx.x;
  int k0 = (bx & 15) * 32;
  int n0 = (bx >> 4) * 32;
  int r = threadIdx.x >> 5;
  int c = threadIdx.x & 31;
  #pragma unroll
  for (int i = 0; i < 4; ++i) {
    int rr = r + i * 8;
    tile[rr][c] = Wx[(size_t)(k0 + rr) * NG + n0 + c];
  }
  __syncthreads();
  #pragma unroll
  for (int i = 0; i < 4; ++i) {
    int rr = r + i * 8;
    WxT[(size_t)(n0 + rr) * DD + k0 + c] = (unsigned short)f2bf(tile[c][rr]);
  }
}

// ---- legacy standalone xproj GEMM (fallback when ws lacks done[] space) ----
__global__ __launch_bounds__(256) void gemm_xproj(
    const float* __restrict__ X,
    const unsigned short* __restrict__ WxT,  // [n][k] bf16
    const float* __restrict__ bias,
    unsigned short* __restrict__ xp) {
  __shared__ short As[128][72];
  __shared__ short Bs[128][72];
  const int tid  = threadIdx.x;
  const int lane = tid & 63;
  const int wave = tid >> 6;
  const int quad = lane >> 4;
  const int l15  = lane & 15;
  const int wm = wave >> 1, wn = wave & 1;
  const int bid = blockIdx.x;
  const int m0 = (bid >> 3) * 128;
  const int n0 = (bid & 7) * 128;

  f32x4 acc[4][4];
  #pragma unroll
  for (int i = 0; i < 4; ++i)
    #pragma unroll
    for (int j = 0; j < 4; ++j) acc[i][j] = (f32x4){0.f, 0.f, 0.f, 0.f};

  for (int kt = 0; kt < 8; ++kt) {
    const int k0 = kt * 64;
    #pragma unroll
    for (int jj = 0; jj < 4; ++jj) {
      int c = tid + jj * 256;
      int row = c >> 3;
      int kc = (c & 7) * 8;
      const float4* src = (const float4*)(X + (size_t)(m0 + row) * DD + k0 + kc);
      float4 v0 = src[0];
      float4 v1 = src[1];
      bf8 tv;
      tv[0] = f2bf(v0.x); tv[1] = f2bf(v0.y); tv[2] = f2bf(v0.z); tv[3] = f2bf(v0.w);
      tv[4] = f2bf(v1.x); tv[5] = f2bf(v1.y); tv[6] = f2bf(v1.z); tv[7] = f2bf(v1.w);
      *(bf8*)&As[row][kc] = tv;
      const uint4* bsrc = (const uint4*)(WxT + (size_t)(n0 + row) * DD + k0 + kc);
      *(uint4*)&Bs[row][kc] = *bsrc;
    }
    __syncthreads();
    #pragma unroll
    for (int ks = 0; ks < 2; ++ks) {
      bf8 a[4], b[4];
      #pragma unroll
      for (int mt = 0; mt < 4; ++mt)
        a[mt] = *(const bf8*)&As[wm * 64 + mt * 16 + l15][ks * 32 + quad * 8];
      #pragma unroll
      for (int nt = 0; nt < 4; ++nt)
        b[nt] = *(const bf8*)&Bs[wn * 64 + nt * 16 + l15][ks * 32 + quad * 8];
      #pragma unroll
      for (int mt = 0; mt < 4; ++mt)
        #pragma unroll
        for (int nt = 0; nt < 4; ++nt)
          acc[mt][nt] = __builtin_amdgcn_mfma_f32_16x16x32_bf16(a[mt], b[nt], acc[mt][nt], 0, 0, 0);
    }
    __syncthreads();
  }
  #pragma unroll
  for (int mt = 0; mt < 4; ++mt)
    #pragma unroll
    for (int nt = 0; nt < 4; ++nt) {
      int col = n0 + wn * 64 + nt * 16 + l15;
      float bv = bias[col];
      #pragma unroll
      for (int r = 0; r < 4; ++r) {
        int row = m0 + wm * 64 + mt * 16 + quad * 4 + r;
        xp[(size_t)row * NG + col] = (unsigned short)f2bf(acc[mt][nt][r] + bv);
      }
    }
}

// ---- shared scan body ----
// FUSED: also gate each step's xp reads on the producer's done[t] tags
// (lookahead-sampled one step early so the steady-state cost is just the
// acquire fence, not an LLC load).
template <bool FUSED>
static __device__ __forceinline__ void scan_body(
    char* smem,
    const unsigned short* __restrict__ xp,
    const int* __restrict__ is_new,
    const float* __restrict__ carry_c,
    const float* __restrict__ carry_h,
    const float* __restrict__ Wh,
    const float* __restrict__ Wa,
    const float* __restrict__ ba,
    const float* __restrict__ Wv,
    const float* __restrict__ bv,
    float* __restrict__ out,
    unsigned int* __restrict__ mail,
    unsigned int* __restrict__ done) {
  const int tid  = threadIdx.x;
  const int lane = tid & 63;
  const int w    = tid >> 6;          // wave 0..7
  const int quad = (lane >> 4);
  const int l15  = lane & 15;
  const int bid  = blockIdx.x;        // 0..31
  const int grp  = bid >> 1;
  const int p    = bid & 1;           // half
  const int s    = p * 8 + w;         // j-slice 0..15
  const int b0   = grp * 16;
  const int j0   = s * 16;

  short (*h_lds)[264]  = (short (*)[264])smem;           // bf16 full rows, +8 pad
  int   (*flag_lds)[16] = (int (*)[16])(smem + 8448);    // dbuf by t&1

  // ---- loop-invariant Wh B-fragments -> 128 VGPRs ----
  bf8 whb[4][8];
  #pragma unroll
  for (int nt = 0; nt < 4; ++nt)
    #pragma unroll
    for (int ks = 0; ks < 8; ++ks)
      #pragma unroll
      for (int j = 0; j < 8; ++j) {
        int k = ks * 32 + quad * 8 + j;            // B-frag: k = quad*8+j, n = lane&15
        int col = nt * 256 + j0 + l15;
        whb[nt][ks][j] = f2bf(Wh[(size_t)k * NG + col]);
      }
  // ---- Wa/Wv B-fragments (head GEMM) ----
  const int astart = (s < 15) ? (2 * s) : 30;
  const int ncols  = (s < 15) ? 2 : 3;
  bf8 wab[8];
  #pragma unroll
  for (int ks = 0; ks < 8; ++ks)
    #pragma unroll
    for (int j = 0; j < 8; ++j) {
      int k = ks * 32 + quad * 8 + j;
      float v = 0.0f;
      if (l15 < ncols) {
        int a = astart + l15;
        v = (a < 32) ? Wa[(size_t)k * 32 + a] : Wv[k];
      }
      wab[ks][j] = f2bf(v);
    }
  float obias = 0.0f;
  if (l15 < ncols) {
    int a = astart + l15;
    obias = (a < 32) ? ba[a] : bv[0];
  }
  // ---- carry c in registers ----
  float c4[4];
  #pragma unroll
  for (int r = 0; r < 4; ++r)
    c4[r] = carry_c[(size_t)(b0 + quad * 4 + r) * HH + j0 + l15];

  const int crow = tid >> 5;          // 0..15
  const int cc0  = (tid & 31) * 4;    // 0..124

  bool rdy = false;                   // done[t] already confirmed (lookahead)

  #pragma unroll 1
  for (int t = 0; t <= TT; ++t) {
    const bool last = (t == TT);
    unsigned short xpraw[16];
    unsigned int dv = 0u;             // lookahead sample of done[t+1]
    if (!last) {
      if constexpr (FUSED) {
        // gate xp[t] reads on producer completion
        if (!rdy) {
          const unsigned int want = 0x5EED0000u | (unsigned)t;
          unsigned int* dp = done + (size_t)t * 16 + l15;
          int g2 = 0;
          for (;;) {
            unsigned int v = __hip_atomic_load(dp, __ATOMIC_RELAXED, __HIP_MEMORY_SCOPE_AGENT);
            if (__all((int)(v == want))) break;
            __builtin_amdgcn_s_sleep(8);
            if (++g2 > (1 << 20)) break;   // anti-hang bailout
          }
        }
        // make producer's xp stores (wbl2'd to LLC) visible: inv L1+L2
        __builtin_amdgcn_fence(__ATOMIC_ACQUIRE, "agent");
      }
      // prefetch xp + reset flags before the mail spin (independent of h)
      #pragma unroll
      for (int nt = 0; nt < 4; ++nt)
        #pragma unroll
        for (int r = 0; r < 4; ++r) {
          size_t row = (size_t)t * BB + b0 + quad * 4 + r;
          xpraw[nt * 4 + r] = xp[row * NG + nt * 256 + j0 + l15];
        }
      if (tid < 16) flag_lds[t & 1][tid] = is_new[t * BB + b0 + tid];
      if constexpr (FUSED) {
        // issue the lookahead sample now; its latency hides under the mail wait
        if (t + 1 < TT)
          dv = __hip_atomic_load(done + (size_t)(t + 1) * 16 + l15,
                                 __ATOMIC_RELAXED, __HIP_MEMORY_SCOPE_AGENT);
      }
    }
    // ---- acquire partner half: poll own 16B of tagged mail ----
    if (t > 0) {
      unsigned long long* mp = (unsigned long long*)
          (mail + ((((size_t)(t & 1) * 16 + grp) * 2 + (1 - p)) * 2048)
                + (size_t)crow * 128 + cc0);
      const unsigned long long M = 0xFFFF0000FFFF0000ull;
      const unsigned long long Wt = ((unsigned long long)(unsigned)t << 16)
                                  | ((unsigned long long)(unsigned)t << 48);
      unsigned long long pv0, pv1;
      int guard = 0;
      for (;;) {
        pv0 = __hip_atomic_load(&mp[0], __ATOMIC_RELAXED, __HIP_MEMORY_SCOPE_AGENT);
        pv1 = __hip_atomic_load(&mp[1], __ATOMIC_RELAXED, __HIP_MEMORY_SCOPE_AGENT);
        bool ok = ((pv0 & M) == Wt) && ((pv1 & M) == Wt);
        if (__all((int)ok)) break;
        __builtin_amdgcn_s_sleep(1);
        if (++guard > (1 << 24)) break;   // anti-hang bailout
      }
      __atomic_signal_fence(__ATOMIC_ACQUIRE);
      unsigned long long packed =
            (pv0 & 0xFFFFull)
          | (((pv0 >> 32) & 0xFFFFull) << 16)
          | ((pv1 & 0xFFFFull) << 32)
          | (((pv1 >> 32) & 0xFFFFull) << 48);
      *(unsigned long long*)&h_lds[crow][(1 - p) * 128 + cc0] = packed;
    } else {
      // t==0: stage full rows from carry_h (fp32 -> bf16)
      int row  = tid >> 5;
      int col0 = (tid & 31) * 8;
      const float4* src = (const float4*)(carry_h + (size_t)(b0 + row) * HH + col0);
      float4 a = src[0], b4 = src[1];
      bf8 tv;
      tv[0] = f2bf(a.x);  tv[1] = f2bf(a.y);  tv[2] = f2bf(a.z);  tv[3] = f2bf(a.w);
      tv[4] = f2bf(b4.x); tv[5] = f2bf(b4.y); tv[6] = f2bf(b4.z); tv[7] = f2bf(b4.w);
      *(bf8*)&h_lds[row][col0] = tv;
    }
    __syncthreads();   // B2: staging complete
    // ---- A-fragments of h ----
    bf8 af[8];
    #pragma unroll
    for (int ks = 0; ks < 8; ++ks)
      af[ks] = *(const bf8*)&h_lds[l15][ks * 32 + quad * 8];
    __syncthreads();   // B3: reads done -> own half writable below
    if (!last) {
      // ---- z = h @ Wh ----
      f32x4 zacc[4];
      #pragma unroll
      for (int nt = 0; nt < 4; ++nt) zacc[nt] = (f32x4){0.f, 0.f, 0.f, 0.f};
      #pragma unroll
      for (int ks = 0; ks < 8; ++ks)
        #pragma unroll
        for (int nt = 0; nt < 4; ++nt)
          zacc[nt] = __builtin_amdgcn_mfma_f32_16x16x32_bf16(af[ks], whb[nt][ks], zacc[nt], 0, 0, 0);
      // ---- gates; episode reset folded in at the gate level ----
      unsigned int* mout = mail + ((((size_t)((t + 1) & 1) * 16 + grp) * 2 + p) * 2048);
      const unsigned int tag = (unsigned int)(t + 1) << 16;
      #pragma unroll
      for (int r = 0; r < 4; ++r) {
        int fr = flag_lds[t & 1][quad * 4 + r];
        float zi = (fr ? 0.0f : zacc[0][r]) + bf2f(xpraw[0 * 4 + r]);
        float zf = (fr ? 0.0f : zacc[1][r]) + bf2f(xpraw[1 * 4 + r]);
        float zg = (fr ? 0.0f : zacc[2][r]) + bf2f(xpraw[2 * 4 + r]);
        float zo = (fr ? 0.0f : zacc[3][r]) + bf2f(xpraw[3 * 4 + r]);
        float ce = fr ? 0.0f : c4[r];
        float ncv = sigf(zf) * ce + sigf(zi) * tanh_(zg);
        c4[r] = ncv;
        float nh = sigf(zo) * tanh_(ncv);
        unsigned short hv = (unsigned short)f2bf(nh);
        int row = quad * 4 + r;
        h_lds[row][j0 + l15] = (short)hv;                 // own half, block-local
        __hip_atomic_store(&mout[(size_t)row * 128 + w * 16 + l15],
                           (unsigned int)hv | tag,
                           __ATOMIC_RELAXED, __HIP_MEMORY_SCOPE_AGENT);
      }
    }
    if constexpr (FUSED) {
      rdy = (!last && (t + 1 < TT))
          ? (bool)__all((int)(dv == (0x5EED0000u | (unsigned)(t + 1))))
          : false;
    }
    // ---- heads + out for step t-1 AFTER the h handoff: off critical path ----
    if (t > 0) {
      f32x4 oacc = {0.f, 0.f, 0.f, 0.f};
      #pragma unroll
      for (int ks = 0; ks < 8; ++ks)
        oacc = __builtin_amdgcn_mfma_f32_16x16x32_bf16(af[ks], wab[ks], oacc, 0, 0, 0);
      if (l15 < ncols) {
        #pragma unroll
        for (int r = 0; r < 4; ++r) {
          size_t orow = (size_t)(t - 1) * BB + b0 + quad * 4 + r;
          out[orow * 33 + astart + l15] = oacc[r] + obias;
        }
      }
    }
  }
}

// legacy standalone scan (fallback)
__global__ __launch_bounds__(512, 1) void scan_kernel(
    const unsigned short* __restrict__ xp,
    const int* __restrict__ is_new,
    const float* __restrict__ carry_c,
    const float* __restrict__ carry_h,
    const float* __restrict__ Wh,
    const float* __restrict__ Wa,
    const float* __restrict__ ba,
    const float* __restrict__ Wv,
    const float* __restrict__ bv,
    float* __restrict__ out,
    unsigned int* __restrict__ mail) {
  __shared__ __align__(16) char smem[8576];
  scan_body<false>(smem, xp, is_new, carry_c, carry_h, Wh, Wa, ba, Wv, bv,
                   out, mail, nullptr);
}

// ---- fused producer-consumer kernel ----
// blocks 0..31: persistent scan (dispatched first -> resident immediately).
// blocks 32..8223: 128x128 xproj GEMM tiles, 512 threads (8 waves, 4m x 2n),
// each signals done[t][slot] after a release fence (buffer_wbl2 -> LLC).
// Scan VGPR pressure (~240/wave incl AGPRs) forces 1 block/CU, so GEMM blocks
// never co-reside with scan blocks and cannot steal their issue slots.
__global__ __launch_bounds__(512, 1) void fused_kernel(
    const float* __restrict__ X,
    const unsigned short* __restrict__ WxT,
    const float* __restrict__ bias,
    unsigned short* __restrict__ xp,
    const int* __restrict__ is_new,
    const float* __restrict__ carry_c,
    const float* __restrict__ carry_h,
    const float* __restrict__ Wh,
    const float* __restrict__ Wa,
    const float* __restrict__ ba,
    const float* __restrict__ Wv,
    const float* __restrict__ bv,
    float* __restrict__ out,
    unsigned int* __restrict__ mail,
    unsigned int* __restrict__ done) {
  __shared__ __align__(16) char smem[36864];
  const int tid = threadIdx.x;
  if (blockIdx.x >= 32) {
    // ---------------- GEMM producer ----------------
    short (*As)[72] = (short (*)[72])smem;
    short (*Bs)[72] = (short (*)[72])(smem + 18432);
    const int lane = tid & 63;
    const int wave = tid >> 6;        // 0..7
    const int quad = lane >> 4;
    const int l15  = lane & 15;
    const int wm = wave >> 1;         // 0..3  (32 rows each)
    const int wn = wave & 1;          // 0..1  (64 cols each)
    const int bid_g = (int)blockIdx.x - 32;
    const int mtile = bid_g >> 3;     // 0..1023
    const int nb    = bid_g & 7;
    const int m0 = mtile * 128;
    const int n0 = nb * 128;

    f32x4 acc[2][4];
    #pragma unroll
    for (int i = 0; i < 2; ++i)
      #pragma unroll
      for (int j = 0; j < 4; ++j) acc[i][j] = (f32x4){0.f, 0.f, 0.f, 0.f};

    for (int kt = 0; kt < 8; ++kt) {
      const int k0 = kt * 64;
      #pragma unroll
      for (int jj = 0; jj < 2; ++jj) {
        int c = tid + jj * 512;       // 1024 16B-chunks
        int row = c >> 3;
        int kc = (c & 7) * 8;
        const float4* src = (const float4*)(X + (size_t)(m0 + row) * DD + k0 + kc);
        float4 v0 = src[0];
        float4 v1 = src[1];
        bf8 tv;
        tv[0] = f2bf(v0.x); tv[1] = f2bf(v0.y); tv[2] = f2bf(v0.z); tv[3] = f2bf(v0.w);
        tv[4] = f2bf(v1.x); tv[5] = f2bf(v1.y); tv[6] = f2bf(v1.z); tv[7] = f2bf(v1.w);
        *(bf8*)&As[row][kc] = tv;
        const uint4* bsrc = (const uint4*)(WxT + (size_t)(n0 + row) * DD + k0 + kc);
        *(uint4*)&Bs[row][kc] = *bsrc;
      }
      __syncthreads();
      #pragma unroll
      for (int ks = 0; ks < 2; ++ks) {
        bf8 a[2], b[4];
        #pragma unroll
        for (int mt = 0; mt < 2; ++mt)
          a[mt] = *(const bf8*)&As[wm * 32 + mt * 16 + l15][ks * 32 + quad * 8];
        #pragma unroll
        for (int nt = 0; nt < 4; ++nt)
          b[nt] = *(const bf8*)&Bs[wn * 64 + nt * 16 + l15][ks * 32 + quad * 8];
        #pragma unroll
        for (int mt = 0; mt < 2; ++mt)
          #pragma unroll
          for (int nt = 0; nt < 4; ++nt)
            acc[mt][nt] = __builtin_amdgcn_mfma_f32_16x16x32_bf16(a[mt], b[nt], acc[mt][nt], 0, 0, 0);
      }
      __syncthreads();
    }
    #pragma unroll
    for (int mt = 0; mt < 2; ++mt)
      #pragma unroll
      for (int nt = 0; nt < 4; ++nt) {
        int col = n0 + wn * 64 + nt * 16 + l15;
        float bvv = bias[col];
        #pragma unroll
        for (int r = 0; r < 4; ++r) {
          int row = m0 + wm * 32 + mt * 16 + quad * 4 + r;
          xp[(size_t)row * NG + col] = (unsigned short)f2bf(acc[mt][nt][r] + bvv);
        }
      }
    __syncthreads();  // drains vmcnt(0) per wave: all xp stores retired to L2
    if (tid == 0) {
      __builtin_amdgcn_fence(__ATOMIC_RELEASE, "agent");  // wbl2: L2 -> LLC
      const int t16  = mtile >> 1;
      const int slot = (mtile & 1) * 8 + nb;
      __hip_atomic_store(&done[(size_t)t16 * 16 + slot],
                         0x5EED0000u | (unsigned)t16,
                         __ATOMIC_RELAXED, __HIP_MEMORY_SCOPE_AGENT);
    }
    return;
  }
  // ---------------- scan consumer ----------------
  scan_body<true>(smem, xp, is_new, carry_c, carry_h, Wh, Wa, ba, Wv, bv,
                  out, mail, done);
}

extern "C" void kernel_launch(void* const* d_in, const int* in_sizes, int n_in,
                              void* d_out, int out_size, void* d_ws, size_t ws_size,
                              hipStream_t stream) {
  const float* X       = (const float*)d_in[0];
  const int* is_new    = (const int*)d_in[1];
  const float* carry_c = (const float*)d_in[2];
  const float* carry_h = (const float*)d_in[3];
  const float* Wx      = (const float*)d_in[4];
  const float* Wh      = (const float*)d_in[5];
  const float* b       = (const float*)d_in[6];
  const float* Wa      = (const float*)d_in[7];
  const float* ba      = (const float*)d_in[8];
  const float* Wv      = (const float*)d_in[9];
  const float* bv      = (const float*)d_in[10];
  float* out = (float*)d_out;
  char* ws = (char*)d_ws;
  if (ws_size < WS_NEEDED) return;  // diagnostic: out stays poisoned
  unsigned short* xp   = (unsigned short*)(ws + XP_OFF);
  unsigned short* WxT  = (unsigned short*)(ws + WXT_OFF);
  unsigned int* mail   = (unsigned int*)(ws + MAIL_OFF);

  hipLaunchKernelGGL(transpose_wx_kernel, dim3(512), dim3(256), 0, stream, Wx, WxT);
  if (ws_size >= WS_NEEDED_FUSE) {
    unsigned int* done = (unsigned int*)(ws + DONE_OFF);
    hipLaunchKernelGGL(fused_kernel, dim3(32 + 8192), dim3(512), 0, stream,
                       X, WxT, b, xp, is_new, carry_c, carry_h, Wh, Wa, ba, Wv, bv,
                       out, mail, done);
  } else {
    hipLaunchKernelGGL(gemm_xproj, dim3(8192), dim3(256), 0, stream, X, WxT, b, xp);
    hipLaunchKernelGGL(scan_kernel, dim3(32), dim3(512), 0, stream,
                       xp, is_new, carry_c, carry_h, Wh, Wa, ba, Wv, bv, out, mail);
  }
}

// Round 2
// 2467.449 us; speedup vs baseline: 1.2042x; 1.2042x over previous
//
#include <hip/hip_runtime.h>
#include <hip/hip_bf16.h>
#include <stdint.h>

#define TT 512
#define BB 256
#define DD 512
#define HH 256
#define AA 32
#define NG 1024  // 4*H

using f32x4 = __attribute__((ext_vector_type(4))) float;
using bf8   = __attribute__((ext_vector_type(8))) short;

static __device__ __forceinline__ short f2bf(float f) {
  union { float f; uint32_t u; } v; v.f = f;
  uint32_t u = v.u;
  u = u + 0x7fffu + ((u >> 16) & 1u);   // round-to-nearest-even
  return (short)(u >> 16);
}
static __device__ __forceinline__ float bf2f(unsigned short s) {
  union { uint32_t u; float f; } v; v.u = ((uint32_t)s) << 16;
  return v.f;
}
static __device__ __forceinline__ float sigf(float x) {
  return 1.0f / (1.0f + __expf(-x));
}
static __device__ __forceinline__ float tanh_(float x) {
  float e = __expf(2.0f * x);
  return 1.0f - 2.0f / (e + 1.0f);   // safe at +/-inf
}

// ---- workspace layout ----
static constexpr size_t XP_OFF    = 0;                              // bf16 [T*B][1024]
static constexpr size_t XP_BYTES  = (size_t)TT * BB * NG * 2;       // 268435456
static constexpr size_t WXT_OFF   = XP_OFF + XP_BYTES;              // bf16 [1024][512]
static constexpr size_t WXT_BYTES = (size_t)NG * DD * 2;            // 1048576
// tagged mail: u32 {low16 = bf16 h, high16 = tag = t+1}
// [parity 2][grp 16][half 2][row 16][hcol 128]
static constexpr size_t MAIL_OFF  = WXT_OFF + WXT_BYTES;
static constexpr size_t MAIL_BYTES= (size_t)2 * 16 * 2 * 16 * 128 * 4;  // 524288
// per-timestep xp readiness tags: u32 done[T][16], value 0x5EED0000|t.
// Poison 0xAAAAAAAA never matches; no init needed (harness poisons ws).
static constexpr size_t DONE_OFF   = MAIL_OFF + MAIL_BYTES;
static constexpr size_t DONE_BYTES = (size_t)TT * 16 * 4;           // 32768
static constexpr size_t WS_NEEDED      = MAIL_OFF + MAIL_BYTES;     // legacy path
static constexpr size_t WS_NEEDED_FUSE = DONE_OFF + DONE_BYTES;     // fused path

// Wx [512][1024] fp32 -> WxT [1024][512] bf16
__global__ __launch_bounds__(256) void transpose_wx_kernel(
    const float* __restrict__ Wx, unsigned short* __restrict__ WxT) {
  __shared__ float tile[32][33];
  int bx = blockIdx.x;
  int k0 = (bx & 15) * 32;
  int n0 = (bx >> 4) * 32;
  int r = threadIdx.x >> 5;
  int c = threadIdx.x & 31;
  #pragma unroll
  for (int i = 0; i < 4; ++i) {
    int rr = r + i * 8;
    tile[rr][c] = Wx[(size_t)(k0 + rr) * NG + n0 + c];
  }
  __syncthreads();
  #pragma unroll
  for (int i = 0; i < 4; ++i) {
    int rr = r + i * 8;
    WxT[(size_t)(n0 + rr) * DD + k0 + c] = (unsigned short)f2bf(tile[c][rr]);
  }
}

// ---- legacy standalone xproj GEMM (fallback when ws lacks done[] space) ----
__global__ __launch_bounds__(256) void gemm_xproj(
    const float* __restrict__ X,
    const unsigned short* __restrict__ WxT,  // [n][k] bf16
    const float* __restrict__ bias,
    unsigned short* __restrict__ xp) {
  __shared__ short As[128][72];
  __shared__ short Bs[128][72];
  const int tid  = threadIdx.x;
  const int lane = tid & 63;
  const int wave = tid >> 6;
  const int quad = lane >> 4;
  const int l15  = lane & 15;
  const int wm = wave >> 1, wn = wave & 1;
  const int bid = blockIdx.x;
  const int m0 = (bid >> 3) * 128;
  const int n0 = (bid & 7) * 128;

  f32x4 acc[4][4];
  #pragma unroll
  for (int i = 0; i < 4; ++i)
    #pragma unroll
    for (int j = 0; j < 4; ++j) acc[i][j] = (f32x4){0.f, 0.f, 0.f, 0.f};

  for (int kt = 0; kt < 8; ++kt) {
    const int k0 = kt * 64;
    #pragma unroll
    for (int jj = 0; jj < 4; ++jj) {
      int c = tid + jj * 256;
      int row = c >> 3;
      int kc = (c & 7) * 8;
      const float4* src = (const float4*)(X + (size_t)(m0 + row) * DD + k0 + kc);
      float4 v0 = src[0];
      float4 v1 = src[1];
      bf8 tv;
      tv[0] = f2bf(v0.x); tv[1] = f2bf(v0.y); tv[2] = f2bf(v0.z); tv[3] = f2bf(v0.w);
      tv[4] = f2bf(v1.x); tv[5] = f2bf(v1.y); tv[6] = f2bf(v1.z); tv[7] = f2bf(v1.w);
      *(bf8*)&As[row][kc] = tv;
      const uint4* bsrc = (const uint4*)(WxT + (size_t)(n0 + row) * DD + k0 + kc);
      *(uint4*)&Bs[row][kc] = *bsrc;
    }
    __syncthreads();
    #pragma unroll
    for (int ks = 0; ks < 2; ++ks) {
      bf8 a[4], b[4];
      #pragma unroll
      for (int mt = 0; mt < 4; ++mt)
        a[mt] = *(const bf8*)&As[wm * 64 + mt * 16 + l15][ks * 32 + quad * 8];
      #pragma unroll
      for (int nt = 0; nt < 4; ++nt)
        b[nt] = *(const bf8*)&Bs[wn * 64 + nt * 16 + l15][ks * 32 + quad * 8];
      #pragma unroll
      for (int mt = 0; mt < 4; ++mt)
        #pragma unroll
        for (int nt = 0; nt < 4; ++nt)
          acc[mt][nt] = __builtin_amdgcn_mfma_f32_16x16x32_bf16(a[mt], b[nt], acc[mt][nt], 0, 0, 0);
    }
    __syncthreads();
  }
  #pragma unroll
  for (int mt = 0; mt < 4; ++mt)
    #pragma unroll
    for (int nt = 0; nt < 4; ++nt) {
      int col = n0 + wn * 64 + nt * 16 + l15;
      float bv = bias[col];
      #pragma unroll
      for (int r = 0; r < 4; ++r) {
        int row = m0 + wm * 64 + mt * 16 + quad * 4 + r;
        xp[(size_t)row * NG + col] = (unsigned short)f2bf(acc[mt][nt][r] + bv);
      }
    }
}

// ---- shared scan body ----
// FUSED: gate each step's xp reads on the producer's done[t] tags.
// NO hardware acquire fence: each xp element is read exactly once, only after
// done[t] is confirmed. Intra-kernel, the only prior toucher of an xp line is
// its producer (same XCD -> shared L2, fresh; other XCD -> clean miss -> LLC,
// which is valid because the producer's release fence (buffer_wbl2) precedes
// the tag store). Pre-kernel dirty lines are flushed at dispatch boundaries.
// Only a compiler fence is needed to pin load order. (Round-1's per-step
// agent-acquire fence cost ~870us: buffer_inv trashed XCD L2s -> +700MB HBM
// refetch + fence latency on the critical path.)
template <bool FUSED>
static __device__ __forceinline__ void scan_body(
    char* smem,
    const unsigned short* __restrict__ xp,
    const int* __restrict__ is_new,
    const float* __restrict__ carry_c,
    const float* __restrict__ carry_h,
    const float* __restrict__ Wh,
    const float* __restrict__ Wa,
    const float* __restrict__ ba,
    const float* __restrict__ Wv,
    const float* __restrict__ bv,
    float* __restrict__ out,
    unsigned int* __restrict__ mail,
    unsigned int* __restrict__ done) {
  const int tid  = threadIdx.x;
  const int lane = tid & 63;
  const int w    = tid >> 6;          // wave 0..7
  const int quad = (lane >> 4);
  const int l15  = lane & 15;
  const int bid  = blockIdx.x;        // 0..31
  const int grp  = bid >> 1;
  const int p    = bid & 1;           // half
  const int s    = p * 8 + w;         // j-slice 0..15
  const int b0   = grp * 16;
  const int j0   = s * 16;

  short (*h_lds)[264]  = (short (*)[264])smem;           // bf16 full rows, +8 pad
  int   (*flag_lds)[16] = (int (*)[16])(smem + 8448);    // dbuf by t&1

  // ---- loop-invariant Wh B-fragments -> 128 VGPRs ----
  bf8 whb[4][8];
  #pragma unroll
  for (int nt = 0; nt < 4; ++nt)
    #pragma unroll
    for (int ks = 0; ks < 8; ++ks)
      #pragma unroll
      for (int j = 0; j < 8; ++j) {
        int k = ks * 32 + quad * 8 + j;            // B-frag: k = quad*8+j, n = lane&15
        int col = nt * 256 + j0 + l15;
        whb[nt][ks][j] = f2bf(Wh[(size_t)k * NG + col]);
      }
  // ---- Wa/Wv B-fragments (head GEMM) ----
  const int astart = (s < 15) ? (2 * s) : 30;
  const int ncols  = (s < 15) ? 2 : 3;
  bf8 wab[8];
  #pragma unroll
  for (int ks = 0; ks < 8; ++ks)
    #pragma unroll
    for (int j = 0; j < 8; ++j) {
      int k = ks * 32 + quad * 8 + j;
      float v = 0.0f;
      if (l15 < ncols) {
        int a = astart + l15;
        v = (a < 32) ? Wa[(size_t)k * 32 + a] : Wv[k];
      }
      wab[ks][j] = f2bf(v);
    }
  float obias = 0.0f;
  if (l15 < ncols) {
    int a = astart + l15;
    obias = (a < 32) ? ba[a] : bv[0];
  }
  // ---- carry c in registers ----
  float c4[4];
  #pragma unroll
  for (int r = 0; r < 4; ++r)
    c4[r] = carry_c[(size_t)(b0 + quad * 4 + r) * HH + j0 + l15];

  const int crow = tid >> 5;          // 0..15
  const int cc0  = (tid & 31) * 4;    // 0..124

  bool rdy = false;                   // done[t] already confirmed (lookahead)

  #pragma unroll 1
  for (int t = 0; t <= TT; ++t) {
    const bool last = (t == TT);
    unsigned short xpraw[16];
    unsigned int dv = 0u;             // lookahead sample of done[t+1]
    if (!last) {
      if constexpr (FUSED) {
        // gate xp[t] reads on producer completion
        if (!rdy) {
          const unsigned int want = 0x5EED0000u | (unsigned)t;
          unsigned int* dp = done + (size_t)t * 16 + l15;
          int g2 = 0;
          for (;;) {
            unsigned int v = __hip_atomic_load(dp, __ATOMIC_RELAXED, __HIP_MEMORY_SCOPE_AGENT);
            if (__all((int)(v == want))) break;
            __builtin_amdgcn_s_sleep(8);
            if (++g2 > (1 << 20)) break;   // anti-hang bailout
          }
        }
        // compiler fence only: keep the xp loads below the gate
        __atomic_signal_fence(__ATOMIC_ACQUIRE);
      }
      // prefetch xp + reset flags before the mail spin (independent of h)
      #pragma unroll
      for (int nt = 0; nt < 4; ++nt)
        #pragma unroll
        for (int r = 0; r < 4; ++r) {
          size_t row = (size_t)t * BB + b0 + quad * 4 + r;
          xpraw[nt * 4 + r] = xp[row * NG + nt * 256 + j0 + l15];
        }
      if (tid < 16) flag_lds[t & 1][tid] = is_new[t * BB + b0 + tid];
      if constexpr (FUSED) {
        // issue the lookahead sample now; its latency hides under the mail wait
        if (t + 1 < TT)
          dv = __hip_atomic_load(done + (size_t)(t + 1) * 16 + l15,
                                 __ATOMIC_RELAXED, __HIP_MEMORY_SCOPE_AGENT);
      }
    }
    // ---- acquire partner half: poll own 16B of tagged mail ----
    if (t > 0) {
      unsigned long long* mp = (unsigned long long*)
          (mail + ((((size_t)(t & 1) * 16 + grp) * 2 + (1 - p)) * 2048)
                + (size_t)crow * 128 + cc0);
      const unsigned long long M = 0xFFFF0000FFFF0000ull;
      const unsigned long long Wt = ((unsigned long long)(unsigned)t << 16)
                                  | ((unsigned long long)(unsigned)t << 48);
      unsigned long long pv0, pv1;
      int guard = 0;
      for (;;) {
        pv0 = __hip_atomic_load(&mp[0], __ATOMIC_RELAXED, __HIP_MEMORY_SCOPE_AGENT);
        pv1 = __hip_atomic_load(&mp[1], __ATOMIC_RELAXED, __HIP_MEMORY_SCOPE_AGENT);
        bool ok = ((pv0 & M) == Wt) && ((pv1 & M) == Wt);
        if (__all((int)ok)) break;
        __builtin_amdgcn_s_sleep(1);
        if (++guard > (1 << 24)) break;   // anti-hang bailout
      }
      __atomic_signal_fence(__ATOMIC_ACQUIRE);
      unsigned long long packed =
            (pv0 & 0xFFFFull)
          | (((pv0 >> 32) & 0xFFFFull) << 16)
          | ((pv1 & 0xFFFFull) << 32)
          | (((pv1 >> 32) & 0xFFFFull) << 48);
      *(unsigned long long*)&h_lds[crow][(1 - p) * 128 + cc0] = packed;
    } else {
      // t==0: stage full rows from carry_h (fp32 -> bf16)
      int row  = tid >> 5;
      int col0 = (tid & 31) * 8;
      const float4* src = (const float4*)(carry_h + (size_t)(b0 + row) * HH + col0);
      float4 a = src[0], b4 = src[1];
      bf8 tv;
      tv[0] = f2bf(a.x);  tv[1] = f2bf(a.y);  tv[2] = f2bf(a.z);  tv[3] = f2bf(a.w);
      tv[4] = f2bf(b4.x); tv[5] = f2bf(b4.y); tv[6] = f2bf(b4.z); tv[7] = f2bf(b4.w);
      *(bf8*)&h_lds[row][col0] = tv;
    }
    __syncthreads();   // B2: staging complete
    // ---- A-fragments of h ----
    bf8 af[8];
    #pragma unroll
    for (int ks = 0; ks < 8; ++ks)
      af[ks] = *(const bf8*)&h_lds[l15][ks * 32 + quad * 8];
    __syncthreads();   // B3: reads done -> own half writable below
    if (!last) {
      // ---- z = h @ Wh ----
      f32x4 zacc[4];
      #pragma unroll
      for (int nt = 0; nt < 4; ++nt) zacc[nt] = (f32x4){0.f, 0.f, 0.f, 0.f};
      #pragma unroll
      for (int ks = 0; ks < 8; ++ks)
        #pragma unroll
        for (int nt = 0; nt < 4; ++nt)
          zacc[nt] = __builtin_amdgcn_mfma_f32_16x16x32_bf16(af[ks], whb[nt][ks], zacc[nt], 0, 0, 0);
      // ---- gates; episode reset folded in at the gate level ----
      unsigned int* mout = mail + ((((size_t)((t + 1) & 1) * 16 + grp) * 2 + p) * 2048);
      const unsigned int tag = (unsigned int)(t + 1) << 16;
      #pragma unroll
      for (int r = 0; r < 4; ++r) {
        int fr = flag_lds[t & 1][quad * 4 + r];
        float zi = (fr ? 0.0f : zacc[0][r]) + bf2f(xpraw[0 * 4 + r]);
        float zf = (fr ? 0.0f : zacc[1][r]) + bf2f(xpraw[1 * 4 + r]);
        float zg = (fr ? 0.0f : zacc[2][r]) + bf2f(xpraw[2 * 4 + r]);
        float zo = (fr ? 0.0f : zacc[3][r]) + bf2f(xpraw[3 * 4 + r]);
        float ce = fr ? 0.0f : c4[r];
        float ncv = sigf(zf) * ce + sigf(zi) * tanh_(zg);
        c4[r] = ncv;
        float nh = sigf(zo) * tanh_(ncv);
        unsigned short hv = (unsigned short)f2bf(nh);
        int row = quad * 4 + r;
        h_lds[row][j0 + l15] = (short)hv;                 // own half, block-local
        __hip_atomic_store(&mout[(size_t)row * 128 + w * 16 + l15],
                           (unsigned int)hv | tag,
                           __ATOMIC_RELAXED, __HIP_MEMORY_SCOPE_AGENT);
      }
    }
    if constexpr (FUSED) {
      rdy = (!last && (t + 1 < TT))
          ? (bool)__all((int)(dv == (0x5EED0000u | (unsigned)(t + 1))))
          : false;
    }
    // ---- heads + out for step t-1 AFTER the h handoff: off critical path ----
    if (t > 0) {
      f32x4 oacc = {0.f, 0.f, 0.f, 0.f};
      #pragma unroll
      for (int ks = 0; ks < 8; ++ks)
        oacc = __builtin_amdgcn_mfma_f32_16x16x32_bf16(af[ks], wab[ks], oacc, 0, 0, 0);
      if (l15 < ncols) {
        #pragma unroll
        for (int r = 0; r < 4; ++r) {
          size_t orow = (size_t)(t - 1) * BB + b0 + quad * 4 + r;
          out[orow * 33 + astart + l15] = oacc[r] + obias;
        }
      }
    }
  }
}

// legacy standalone scan (fallback)
__global__ __launch_bounds__(512, 1) void scan_kernel(
    const unsigned short* __restrict__ xp,
    const int* __restrict__ is_new,
    const float* __restrict__ carry_c,
    const float* __restrict__ carry_h,
    const float* __restrict__ Wh,
    const float* __restrict__ Wa,
    const float* __restrict__ ba,
    const float* __restrict__ Wv,
    const float* __restrict__ bv,
    float* __restrict__ out,
    unsigned int* __restrict__ mail) {
  __shared__ __align__(16) char smem[8576];
  scan_body<false>(smem, xp, is_new, carry_c, carry_h, Wh, Wa, ba, Wv, bv,
                   out, mail, nullptr);
}

// ---- fused producer-consumer kernel ----
// blocks 0..31: persistent scan. blocks 32..8223: 128x128 xproj GEMM tiles.
// LDS padded to 84KB (> 160KB/2): EVERY block owns its CU exclusively, so
// GEMM blocks can never co-reside with (and steal issue slots from) the
// latency-critical scan blocks -- the round-1 regression mechanism. GEMM at
// 1 block/CU on ~224 CUs produces ~20 tiles/us vs scan consumption of
// 4.4 tiles/us, so the producer stays ahead and fully hidden.
__global__ __launch_bounds__(512, 1) void fused_kernel(
    const float* __restrict__ X,
    const unsigned short* __restrict__ WxT,
    const float* __restrict__ bias,
    unsigned short* __restrict__ xp,
    const int* __restrict__ is_new,
    const float* __restrict__ carry_c,
    const float* __restrict__ carry_h,
    const float* __restrict__ Wh,
    const float* __restrict__ Wa,
    const float* __restrict__ ba,
    const float* __restrict__ Wv,
    const float* __restrict__ bv,
    float* __restrict__ out,
    unsigned int* __restrict__ mail,
    unsigned int* __restrict__ done) {
  __shared__ __align__(16) char smem[86016];  // 84KB: forces 1 block/CU
  const int tid = threadIdx.x;
  if (blockIdx.x >= 32) {
    // ---------------- GEMM producer ----------------
    short (*As)[72] = (short (*)[72])smem;
    short (*Bs)[72] = (short (*)[72])(smem + 18432);
    const int lane = tid & 63;
    const int wave = tid >> 6;        // 0..7
    const int quad = lane >> 4;
    const int l15  = lane & 15;
    const int wm = wave >> 1;         // 0..3  (32 rows each)
    const int wn = wave & 1;          // 0..1  (64 cols each)
    const int bid_g = (int)blockIdx.x - 32;
    const int mtile = bid_g >> 3;     // 0..1023
    const int nb    = bid_g & 7;
    const int m0 = mtile * 128;
    const int n0 = nb * 128;

    f32x4 acc[2][4];
    #pragma unroll
    for (int i = 0; i < 2; ++i)
      #pragma unroll
      for (int j = 0; j < 4; ++j) acc[i][j] = (f32x4){0.f, 0.f, 0.f, 0.f};

    for (int kt = 0; kt < 8; ++kt) {
      const int k0 = kt * 64;
      #pragma unroll
      for (int jj = 0; jj < 2; ++jj) {
        int c = tid + jj * 512;       // 1024 16B-chunks
        int row = c >> 3;
        int kc = (c & 7) * 8;
        const float4* src = (const float4*)(X + (size_t)(m0 + row) * DD + k0 + kc);
        float4 v0 = src[0];
        float4 v1 = src[1];
        bf8 tv;
        tv[0] = f2bf(v0.x); tv[1] = f2bf(v0.y); tv[2] = f2bf(v0.z); tv[3] = f2bf(v0.w);
        tv[4] = f2bf(v1.x); tv[5] = f2bf(v1.y); tv[6] = f2bf(v1.z); tv[7] = f2bf(v1.w);
        *(bf8*)&As[row][kc] = tv;
        const uint4* bsrc = (const uint4*)(WxT + (size_t)(n0 + row) * DD + k0 + kc);
        *(uint4*)&Bs[row][kc] = *bsrc;
      }
      __syncthreads();
      #pragma unroll
      for (int ks = 0; ks < 2; ++ks) {
        bf8 a[2], b[4];
        #pragma unroll
        for (int mt = 0; mt < 2; ++mt)
          a[mt] = *(const bf8*)&As[wm * 32 + mt * 16 + l15][ks * 32 + quad * 8];
        #pragma unroll
        for (int nt = 0; nt < 4; ++nt)
          b[nt] = *(const bf8*)&Bs[wn * 64 + nt * 16 + l15][ks * 32 + quad * 8];
        #pragma unroll
        for (int mt = 0; mt < 2; ++mt)
          #pragma unroll
          for (int nt = 0; nt < 4; ++nt)
            acc[mt][nt] = __builtin_amdgcn_mfma_f32_16x16x32_bf16(a[mt], b[nt], acc[mt][nt], 0, 0, 0);
      }
      __syncthreads();
    }
    #pragma unroll
    for (int mt = 0; mt < 2; ++mt)
      #pragma unroll
      for (int nt = 0; nt < 4; ++nt) {
        int col = n0 + wn * 64 + nt * 16 + l15;
        float bvv = bias[col];
        #pragma unroll
        for (int r = 0; r < 4; ++r) {
          int row = m0 + wm * 32 + mt * 16 + quad * 4 + r;
          xp[(size_t)row * NG + col] = (unsigned short)f2bf(acc[mt][nt][r] + bvv);
        }
      }
    __syncthreads();  // drains vmcnt(0) per wave: all xp stores retired to L2
    if (tid == 0) {
      __builtin_amdgcn_fence(__ATOMIC_RELEASE, "agent");  // wbl2: L2 -> LLC
      const int t16  = mtile >> 1;
      const int slot = (mtile & 1) * 8 + nb;
      __hip_atomic_store(&done[(size_t)t16 * 16 + slot],
                         0x5EED0000u | (unsigned)t16,
                         __ATOMIC_RELAXED, __HIP_MEMORY_SCOPE_AGENT);
    }
    return;
  }
  // ---------------- scan consumer ----------------
  scan_body<true>(smem, xp, is_new, carry_c, carry_h, Wh, Wa, ba, Wv, bv,
                  out, mail, done);
}

extern "C" void kernel_launch(void* const* d_in, const int* in_sizes, int n_in,
                              void* d_out, int out_size, void* d_ws, size_t ws_size,
                              hipStream_t stream) {
  const float* X       = (const float*)d_in[0];
  const int* is_new    = (const int*)d_in[1];
  const float* carry_c = (const float*)d_in[2];
  const float* carry_h = (const float*)d_in[3];
  const float* Wx      = (const float*)d_in[4];
  const float* Wh      = (const float*)d_in[5];
  const float* b       = (const float*)d_in[6];
  const float* Wa      = (const float*)d_in[7];
  const float* ba      = (const float*)d_in[8];
  const float* Wv      = (const float*)d_in[9];
  const float* bv      = (const float*)d_in[10];
  float* out = (float*)d_out;
  char* ws = (char*)d_ws;
  if (ws_size < WS_NEEDED) return;  // diagnostic: out stays poisoned
  unsigned short* xp   = (unsigned short*)(ws + XP_OFF);
  unsigned short* WxT  = (unsigned short*)(ws + WXT_OFF);
  unsigned int* mail   = (unsigned int*)(ws + MAIL_OFF);

  hipLaunchKernelGGL(transpose_wx_kernel, dim3(512), dim3(256), 0, stream, Wx, WxT);
  if (ws_size >= WS_NEEDED_FUSE) {
    unsigned int* done = (unsigned int*)(ws + DONE_OFF);
    hipLaunchKernelGGL(fused_kernel, dim3(32 + 8192), dim3(512), 0, stream,
                       X, WxT, b, xp, is_new, carry_c, carry_h, Wh, Wa, ba, Wv, bv,
                       out, mail, done);
  } else {
    hipLaunchKernelGGL(gemm_xproj, dim3(8192), dim3(256), 0, stream, X, WxT, b, xp);
    hipLaunchKernelGGL(scan_kernel, dim3(32), dim3(512), 0, stream,
                       xp, is_new, carry_c, carry_h, Wh, Wa, ba, Wv, bv, out, mail);
  }
}